// Round 16
// baseline (215.246 us; speedup 1.0000x reference)
//
#include <hip/hip_runtime.h>
#include <cstdint>
#include <cstddef>

#define NROW 8192
#define DIM  512
#define HALF 4096
#define INV_T 12.5f
#define LDSW 64   // unpadded: required by global_load_lds wave-uniform-base layout
#define NTILE 2080

// gfx950 MFMA bf16 builtins take vectors of __bf16.
typedef __bf16 bf16x8  __attribute__((ext_vector_type(8)));
typedef float  floatx4 __attribute__((ext_vector_type(4)));

__device__ __forceinline__ float bf2f_lo(unsigned u) { return __uint_as_float(u << 16); }
__device__ __forceinline__ float bf2f_hi(unsigned u) { return __uint_as_float(u & 0xffff0000u); }
__device__ __forceinline__ unsigned short f2bf(float f) {
    unsigned u = __float_as_uint(f);
    u += 0x7fffu + ((u >> 16) & 1u);   // RNE
    return (unsigned short)(u >> 16);
}

// HW fp32 atomic add (no CAS loop), device scope.
__device__ __forceinline__ void atom_addf(float* p, float v) {
    __hip_atomic_fetch_add(p, v, __ATOMIC_RELAXED, __HIP_MEMORY_SCOPE_AGENT);
}

// ---------------- kernel 1: fused normalize + pos + zero ----------------
// GRID = NROW/4. Block b handles rows {2b, 2b+1, 2b+4096, 2b+4097} (one/wave).
// z stored XOR-swizzled: piece' = piece ^ (row&7) within each 64-elem K-slab
// (kills LDS bank conflicts after verbatim global_load_lds staging).
__global__ void knormpos(const float* __restrict__ x, unsigned short* __restrict__ z,
                         float* __restrict__ pos, float* __restrict__ sumexp,
                         float* __restrict__ cnt, float* __restrict__ nll_acc,
                         int* __restrict__ done) {
    int id = blockIdx.x * 256 + threadIdx.x;
    if (id < NROW) { sumexp[id] = 0.f; cnt[id] = 0.f; }
    if (id == 0) { nll_acc[0] = 0.f; done[0] = 0; }

    __shared__ __align__(16) unsigned short zs[4][512];

    const int w = threadIdx.x >> 6, lane = threadIdx.x & 63;
    const int row = blockIdx.x * 2 + (w & 1) + (w >> 1) * HALF;   // blockIdx < 2048

    const float* xr = x + (size_t)row * DIM + lane * 8;
    float4 v0 = ((const float4*)xr)[0];
    float4 v1 = ((const float4*)xr)[1];
    float ss = v0.x*v0.x + v0.y*v0.y + v0.z*v0.z + v0.w*v0.w
             + v1.x*v1.x + v1.y*v1.y + v1.z*v1.z + v1.w*v1.w;
    #pragma unroll
    for (int m = 1; m < 64; m <<= 1) ss += __shfl_xor(ss, m);
    float inv = 1.0f / fmaxf(sqrtf(ss), 1e-8f);
    uint4 o;
    o.x = (unsigned)f2bf(v0.x * inv) | ((unsigned)f2bf(v0.y * inv) << 16);
    o.y = (unsigned)f2bf(v0.z * inv) | ((unsigned)f2bf(v0.w * inv) << 16);
    o.z = (unsigned)f2bf(v1.x * inv) | ((unsigned)f2bf(v1.y * inv) << 16);
    o.w = (unsigned)f2bf(v1.z * inv) | ((unsigned)f2bf(v1.w * inv) << 16);
    *(uint4*)(&zs[w][lane * 8]) = o;
    int sl = (lane & 56) | ((lane & 7) ^ (row & 7));
    *(uint4*)(z + (size_t)row * DIM + sl * 8) = o;
    __syncthreads();

    if (w < 2) {
        uint4 a = *(const uint4*)(&zs[w][lane * 8]);
        uint4 b = *(const uint4*)(&zs[w + 2][lane * 8]);
        float s = bf2f_lo(a.x)*bf2f_lo(b.x) + bf2f_hi(a.x)*bf2f_hi(b.x)
                + bf2f_lo(a.y)*bf2f_lo(b.y) + bf2f_hi(a.y)*bf2f_hi(b.y)
                + bf2f_lo(a.z)*bf2f_lo(b.z) + bf2f_hi(a.z)*bf2f_hi(b.z)
                + bf2f_lo(a.w)*bf2f_lo(b.w) + bf2f_hi(a.w)*bf2f_hi(b.w);
        #pragma unroll
        for (int m = 1; m < 64; m <<= 1) s += __shfl_xor(s, m);
        if (lane == 0) {
            const int r = blockIdx.x * 2 + w;
            pos[r] = s;
            pos[r + HALF] = s;
        }
    }
}

// ------- kernel 2 (identifier-named): triangular sim GEMM + fused finalize ----
// R14 structure: 512 threads = 8 waves (4x2), each wave 32x64 (acc 2x4 =
// 32 AGPR; VGPR ~44 -> 4 blocks/CU). Supertile order for L2. The LAST block
// (device-scope ticket) performs the finalize: ranks -> out, nll -> out[8192].
__global__ __launch_bounds__(512, 3) void NCELoss_3126736191777_kernel(
        const unsigned short* __restrict__ z, const float* __restrict__ pos,
        float* __restrict__ sumexp, float* __restrict__ cnt,
        float* __restrict__ out, int* __restrict__ done) {
    __shared__ __align__(16) unsigned short As[128 * LDSW];
    __shared__ __align__(16) unsigned short Bs[128 * LDSW];
    __shared__ float pos_r[128];
    __shared__ float pos_c[128];
    __shared__ int lastBlock;
    __shared__ float red[8];

    // ---- supertile decode: b -> (bi, bj), bi <= bj, 64x64 tile grid ----
    const int b = blockIdx.x;
    int I = 0;
    while (b >= 516 * (I + 1) - 32 * (I + 1) * (I + 1)) ++I;
    const int lb = b - (516 * I - 32 * I * I);
    int bi, bj;
    if (lb < 36) {
        int ti = 0;
        while (lb >= 8 * (ti + 1) - (ti + 1) * ti / 2) ++ti;
        const int tj = ti + (lb - (8 * ti - ti * (ti - 1) / 2));
        bi = I * 8 + ti;
        bj = I * 8 + tj;
    } else {
        const int o = lb - 36;
        const int J = I + 1 + (o >> 6);
        bi = I * 8 + ((o & 63) >> 3);
        bj = J * 8 + (o & 7);
    }
    const int r0 = bi * 128;
    const int c0 = bj * 128;
    const bool offdiag = (bi != bj);

    const int t = threadIdx.x;
    const int w = t >> 6, lane = t & 63;
    const int wm = w >> 1, wn = w & 1;          // wm 0..3 (32-row band), wn 0..1 (64-col half)
    const int cid = lane & 15, q = lane >> 4;

    if (t < 128) pos_r[t] = pos[r0 + t];
    else if (t < 256) pos_c[t - 128] = pos[c0 + (t - 128)];

    floatx4 acc[2][4];
    #pragma unroll
    for (int i = 0; i < 2; ++i)
        #pragma unroll
        for (int j = 0; j < 4; ++j)
            acc[i][j] = floatx4{0.f, 0.f, 0.f, 0.f};

    const int lrow8 = lane >> 3;        // 0..7 row within 8-row chunk
    const int lcol  = (lane & 7) * 8;   // piece offset in 64-wide K slab

    for (int kk = 0; kk < 8; ++kk) {
        const int k0 = kk * 64;
        #pragma unroll
        for (int it = 0; it < 2; ++it) {
            const int c = it * 8 + w;                 // chunk 0..15 (8 rows each)
            const unsigned short* gA = z + (size_t)(r0 + c * 8 + lrow8) * DIM + k0 + lcol;
            const unsigned short* gB = z + (size_t)(c0 + c * 8 + lrow8) * DIM + k0 + lcol;
            __builtin_amdgcn_global_load_lds(
                (const __attribute__((address_space(1))) unsigned int*)gA,
                (__attribute__((address_space(3))) unsigned int*)(As + c * 512),
                16, 0, 0);
            __builtin_amdgcn_global_load_lds(
                (const __attribute__((address_space(1))) unsigned int*)gB,
                (__attribute__((address_space(3))) unsigned int*)(Bs + c * 512),
                16, 0, 0);
        }
        __syncthreads();   // drains vmcnt for the async LDS loads
        #pragma unroll
        for (int ks = 0; ks < 2; ++ks) {
            bf16x8 af[2], bfv[4];
            #pragma unroll
            for (int f = 0; f < 2; ++f) {
                const int ar = wm * 32 + f * 16 + cid;
                const int pa = (4 * ks + q) ^ (ar & 7);   // unswizzle
                af[f] = *(const bf16x8*)(As + ar * LDSW + pa * 8);
            }
            #pragma unroll
            for (int f = 0; f < 4; ++f) {
                const int br = wn * 64 + f * 16 + cid;
                const int pb = (4 * ks + q) ^ (br & 7);
                bfv[f] = *(const bf16x8*)(Bs + br * LDSW + pb * 8);
            }
            #pragma unroll
            for (int fm = 0; fm < 2; ++fm)
                #pragma unroll
                for (int fn = 0; fn < 4; ++fn)
                    acc[fm][fn] = __builtin_amdgcn_mfma_f32_16x16x32_bf16(
                        af[fm], bfv[fn], acc[fm][fn], 0, 0, 0);
        }
        __syncthreads();
    }

    // C/D layout: col = lane&15, row = (lane>>4)*4 + reg.
    // ---- epilogue: one exp per element, row + col passes ----
    float col_e[4] = {0.f, 0.f, 0.f, 0.f};
    float col_c[4] = {0.f, 0.f, 0.f, 0.f};
    #pragma unroll
    for (int fm = 0; fm < 2; ++fm) {
        #pragma unroll
        for (int r = 0; r < 4; ++r) {
            const int li = wm * 32 + fm * 16 + q * 4 + r;
            const int i  = r0 + li;
            const float pv = pos_r[li];
            const int pj = (i + HALF) & (NROW - 1);
            float es = 0.f, cs = 0.f;
            #pragma unroll
            for (int fn = 0; fn < 4; ++fn) {
                const int lj = wn * 64 + fn * 16 + cid;
                const int j  = c0 + lj;
                const float s = acc[fm][fn][r];
                const float e = __expf((s - 1.0f) * INV_T);
                const bool dg = (j == i);            // only on diag tiles
                es += dg ? 0.f : e;
                cs += (!dg && (j != pj) && (s > pv)) ? 1.f : 0.f;
                col_e[fn] += e;
                const int pjc = (j + HALF) & (NROW - 1);
                col_c[fn] += ((i != pjc) && (s > pos_c[lj])) ? 1.f : 0.f;
            }
            #pragma unroll
            for (int m = 1; m < 16; m <<= 1) {
                es += __shfl_xor(es, m);
                cs += __shfl_xor(cs, m);
            }
            if (cid == 0) {
                atom_addf(&sumexp[i], es);
                atom_addf(&cnt[i], cs);
            }
        }
    }

    if (offdiag) {
        #pragma unroll
        for (int fn = 0; fn < 4; ++fn) {
            float ec = col_e[fn], cc = col_c[fn];
            ec += __shfl_xor(ec, 16); ec += __shfl_xor(ec, 32);
            cc += __shfl_xor(cc, 16); cc += __shfl_xor(cc, 32);
            if (q == 0) {
                const int j = c0 + wn * 64 + fn * 16 + cid;
                atom_addf(&sumexp[j], ec);
                atom_addf(&cnt[j], cc);
            }
        }
    }

    // ---- fused finalize: last block to finish writes the outputs ----
    if (t == 0) {
        __threadfence();   // release our atomics before the ticket
        int ticket = __hip_atomic_fetch_add(done, 1, __ATOMIC_ACQ_REL,
                                            __HIP_MEMORY_SCOPE_AGENT);
        lastBlock = (ticket == NTILE - 1);
    }
    __syncthreads();
    if (!lastBlock) return;
    __threadfence();       // acquire: all blocks' sumexp/cnt visible

    // Sentinels: pos bad -> 60000 | sumexp==0 -> 40000 | cnt<0 -> 25000 | else rank.
    float local = 0.f;
    #pragma unroll
    for (int rr = 0; rr < NROW / 512; ++rr) {
        const int r = rr * 512 + t;
        float c = cnt[r], se = sumexp[r], p = pos[r];
        float v;
        if (p != p || fabsf(p) > 1.05f) v = 60000.0f;
        else if (se == 0.0f)            v = 40000.0f;
        else if (c < 0.0f)              v = 25000.0f;
        else                            v = c;
        out[r] = v;
        local += -p * INV_T + INV_T + __logf(se);
    }
    #pragma unroll
    for (int m = 1; m < 64; m <<= 1) local += __shfl_xor(local, m);
    if (lane == 0) red[w] = local;
    __syncthreads();
    if (t == 0) {
        float tot = 0.f;
        #pragma unroll
        for (int i = 0; i < 8; ++i) tot += red[i];
        out[NROW] = tot / (float)NROW;
    }
}

extern "C" void kernel_launch(void* const* d_in, const int* in_sizes, int n_in,
                              void* d_out, int out_size, void* d_ws, size_t ws_size,
                              hipStream_t stream) {
    (void)in_sizes; (void)n_in; (void)out_size; (void)ws_size;
    const float* x = (const float*)d_in[0];

    // ws: pos (32 KB) | sumexp (32 KB) | cnt (32 KB) | nll_acc+done (4 KB) | z bf16 (8 MB)
    char* base = (char*)d_ws;
    float* pos     = (float*)(base);
    float* sumexp  = (float*)(base + (size_t)NROW * 4);
    float* cnt     = (float*)(base + (size_t)NROW * 8);
    float* nll_acc = (float*)(base + (size_t)NROW * 12);
    int*   done    = (int*)(base + (size_t)NROW * 12 + 64);
    unsigned short* z = (unsigned short*)(base + (size_t)NROW * 12 + 4096);
    float* out = (float*)d_out;

    knormpos<<<NROW / 4, 256, 0, stream>>>(x, z, pos, sumexp, cnt, nll_acc, done);
    NCELoss_3126736191777_kernel<<<NTILE, 512, 0, stream>>>(z, pos, sumexp, cnt, out, done);
}

// Round 17
// 157.401 us; speedup vs baseline: 1.3675x; 1.3675x over previous
//
#include <hip/hip_runtime.h>
#include <cstdint>
#include <cstddef>

#define NROW 8192
#define DIM  512
#define HALF 4096
#define INV_T 12.5f
#define LDSW 64   // unpadded: required by global_load_lds wave-uniform-base layout

// gfx950 MFMA bf16 builtins take vectors of __bf16.
typedef __bf16 bf16x8  __attribute__((ext_vector_type(8)));
typedef float  floatx4 __attribute__((ext_vector_type(4)));

__device__ __forceinline__ float bf2f_lo(unsigned u) { return __uint_as_float(u << 16); }
__device__ __forceinline__ float bf2f_hi(unsigned u) { return __uint_as_float(u & 0xffff0000u); }
__device__ __forceinline__ unsigned short f2bf(float f) {
    unsigned u = __float_as_uint(f);
    u += 0x7fffu + ((u >> 16) & 1u);   // RNE
    return (unsigned short)(u >> 16);
}

// HW fp32 atomic add (no CAS loop), device scope.
__device__ __forceinline__ void atom_addf(float* p, float v) {
    __hip_atomic_fetch_add(p, v, __ATOMIC_RELAXED, __HIP_MEMORY_SCOPE_AGENT);
}

// ---------------- kernel 1: fused normalize + pos + zero ----------------
// GRID = NROW/4. Block b handles rows {2b, 2b+1, 2b+4096, 2b+4097} (one/wave).
// z stored XOR-swizzled: piece' = piece ^ (row&7) within each 64-elem K-slab
// (kills LDS bank conflicts after verbatim global_load_lds staging).
__global__ void knormpos(const float* __restrict__ x, unsigned short* __restrict__ z,
                         float* __restrict__ pos, float* __restrict__ sumexp,
                         float* __restrict__ cnt, float* __restrict__ nll_acc,
                         int* __restrict__ done) {
    int id = blockIdx.x * 256 + threadIdx.x;
    if (id < NROW) { sumexp[id] = 0.f; cnt[id] = 0.f; }
    if (id == 0) { nll_acc[0] = 0.f; done[0] = 0; }

    __shared__ __align__(16) unsigned short zs[4][512];

    const int w = threadIdx.x >> 6, lane = threadIdx.x & 63;
    const int row = blockIdx.x * 2 + (w & 1) + (w >> 1) * HALF;   // blockIdx < 2048

    const float* xr = x + (size_t)row * DIM + lane * 8;
    float4 v0 = ((const float4*)xr)[0];
    float4 v1 = ((const float4*)xr)[1];
    float ss = v0.x*v0.x + v0.y*v0.y + v0.z*v0.z + v0.w*v0.w
             + v1.x*v1.x + v1.y*v1.y + v1.z*v1.z + v1.w*v1.w;
    #pragma unroll
    for (int m = 1; m < 64; m <<= 1) ss += __shfl_xor(ss, m);
    float inv = 1.0f / fmaxf(sqrtf(ss), 1e-8f);
    uint4 o;
    o.x = (unsigned)f2bf(v0.x * inv) | ((unsigned)f2bf(v0.y * inv) << 16);
    o.y = (unsigned)f2bf(v0.z * inv) | ((unsigned)f2bf(v0.w * inv) << 16);
    o.z = (unsigned)f2bf(v1.x * inv) | ((unsigned)f2bf(v1.y * inv) << 16);
    o.w = (unsigned)f2bf(v1.z * inv) | ((unsigned)f2bf(v1.w * inv) << 16);
    *(uint4*)(&zs[w][lane * 8]) = o;
    int sl = (lane & 56) | ((lane & 7) ^ (row & 7));
    *(uint4*)(z + (size_t)row * DIM + sl * 8) = o;
    __syncthreads();

    if (w < 2) {
        uint4 a = *(const uint4*)(&zs[w][lane * 8]);
        uint4 b = *(const uint4*)(&zs[w + 2][lane * 8]);
        float s = bf2f_lo(a.x)*bf2f_lo(b.x) + bf2f_hi(a.x)*bf2f_hi(b.x)
                + bf2f_lo(a.y)*bf2f_lo(b.y) + bf2f_hi(a.y)*bf2f_hi(b.y)
                + bf2f_lo(a.z)*bf2f_lo(b.z) + bf2f_hi(a.z)*bf2f_hi(b.z)
                + bf2f_lo(a.w)*bf2f_lo(b.w) + bf2f_hi(a.w)*bf2f_hi(b.w);
        #pragma unroll
        for (int m = 1; m < 64; m <<= 1) s += __shfl_xor(s, m);
        if (lane == 0) {
            const int r = blockIdx.x * 2 + w;
            pos[r] = s;
            pos[r + HALF] = s;
        }
    }
}

// ---------------- kernel 2: triangular fused sim GEMM (R14 structure) ---------
// 512 threads = 8 waves (4x2), each wave 32x64 (acc 2x4 = 32 AGPR; VGPR ~44
// -> 4 blocks/CU = 32 waves/CU). Supertile order for L2 locality. kk-loop
// fully unrolled so k0 folds into global_load_lds immediate offsets.
__global__ __launch_bounds__(512, 3) void kgemm(const unsigned short* __restrict__ z,
                                                const float* __restrict__ pos,
                                                float* __restrict__ sumexp,
                                                float* __restrict__ cnt) {
    __shared__ __align__(16) unsigned short As[128 * LDSW];
    __shared__ __align__(16) unsigned short Bs[128 * LDSW];
    __shared__ float pos_r[128];
    __shared__ float pos_c[128];

    // ---- supertile decode: b -> (bi, bj), bi <= bj, 64x64 tile grid ----
    const int b = blockIdx.x;
    int I = 0;
    while (b >= 516 * (I + 1) - 32 * (I + 1) * (I + 1)) ++I;
    const int lb = b - (516 * I - 32 * I * I);
    int bi, bj;
    if (lb < 36) {
        int ti = 0;
        while (lb >= 8 * (ti + 1) - (ti + 1) * ti / 2) ++ti;
        const int tj = ti + (lb - (8 * ti - ti * (ti - 1) / 2));
        bi = I * 8 + ti;
        bj = I * 8 + tj;
    } else {
        const int o = lb - 36;
        const int J = I + 1 + (o >> 6);
        bi = I * 8 + ((o & 63) >> 3);
        bj = J * 8 + (o & 7);
    }
    const int r0 = bi * 128;
    const int c0 = bj * 128;
    const bool offdiag = (bi != bj);

    const int t = threadIdx.x;
    const int w = t >> 6, lane = t & 63;
    const int wm = w >> 1, wn = w & 1;          // wm 0..3 (32-row band), wn 0..1 (64-col half)
    const int cid = lane & 15, q = lane >> 4;

    if (t < 128) pos_r[t] = pos[r0 + t];
    else if (t < 256) pos_c[t - 128] = pos[c0 + (t - 128)];

    floatx4 acc[2][4];
    #pragma unroll
    for (int i = 0; i < 2; ++i)
        #pragma unroll
        for (int j = 0; j < 4; ++j)
            acc[i][j] = floatx4{0.f, 0.f, 0.f, 0.f};

    const int lrow8 = lane >> 3;        // 0..7 row within 8-row chunk
    const int lcol  = (lane & 7) * 8;   // piece offset in 64-wide K slab

    // Loop-invariant per-lane global bases; kk*128-byte offsets become
    // immediates after full unroll (max 896 < 4096 signed-13-bit).
    const unsigned short* gA0 = z + (size_t)(r0 + w * 8 + lrow8) * DIM + lcol;
    const unsigned short* gA1 = z + (size_t)(r0 + (8 + w) * 8 + lrow8) * DIM + lcol;
    const unsigned short* gB0 = z + (size_t)(c0 + w * 8 + lrow8) * DIM + lcol;
    const unsigned short* gB1 = z + (size_t)(c0 + (8 + w) * 8 + lrow8) * DIM + lcol;

    #pragma unroll
    for (int kk = 0; kk < 8; ++kk) {
        const int k0 = kk * 64;
        __builtin_amdgcn_global_load_lds(
            (const __attribute__((address_space(1))) unsigned int*)(gA0 + k0),
            (__attribute__((address_space(3))) unsigned int*)(As + w * 512), 16, 0, 0);
        __builtin_amdgcn_global_load_lds(
            (const __attribute__((address_space(1))) unsigned int*)(gA1 + k0),
            (__attribute__((address_space(3))) unsigned int*)(As + (8 + w) * 512), 16, 0, 0);
        __builtin_amdgcn_global_load_lds(
            (const __attribute__((address_space(1))) unsigned int*)(gB0 + k0),
            (__attribute__((address_space(3))) unsigned int*)(Bs + w * 512), 16, 0, 0);
        __builtin_amdgcn_global_load_lds(
            (const __attribute__((address_space(1))) unsigned int*)(gB1 + k0),
            (__attribute__((address_space(3))) unsigned int*)(Bs + (8 + w) * 512), 16, 0, 0);
        __syncthreads();   // drains vmcnt for the async LDS loads
        #pragma unroll
        for (int ks = 0; ks < 2; ++ks) {
            bf16x8 af[2], bfv[4];
            #pragma unroll
            for (int f = 0; f < 2; ++f) {
                const int ar = wm * 32 + f * 16 + cid;
                const int pa = (4 * ks + q) ^ (ar & 7);   // unswizzle
                af[f] = *(const bf16x8*)(As + ar * LDSW + pa * 8);
            }
            #pragma unroll
            for (int f = 0; f < 4; ++f) {
                const int br = wn * 64 + f * 16 + cid;
                const int pb = (4 * ks + q) ^ (br & 7);
                bfv[f] = *(const bf16x8*)(Bs + br * LDSW + pb * 8);
            }
            #pragma unroll
            for (int fm = 0; fm < 2; ++fm)
                #pragma unroll
                for (int fn = 0; fn < 4; ++fn)
                    acc[fm][fn] = __builtin_amdgcn_mfma_f32_16x16x32_bf16(
                        af[fm], bfv[fn], acc[fm][fn], 0, 0, 0);
        }
        __syncthreads();
    }

    // C/D layout: col = lane&15, row = (lane>>4)*4 + reg.
    // ---- epilogue: one exp per element, row + col passes ----
    float col_e[4] = {0.f, 0.f, 0.f, 0.f};
    float col_c[4] = {0.f, 0.f, 0.f, 0.f};
    #pragma unroll
    for (int fm = 0; fm < 2; ++fm) {
        #pragma unroll
        for (int r = 0; r < 4; ++r) {
            const int li = wm * 32 + fm * 16 + q * 4 + r;
            const int i  = r0 + li;
            const float pv = pos_r[li];
            const int pj = (i + HALF) & (NROW - 1);
            float es = 0.f, cs = 0.f;
            #pragma unroll
            for (int fn = 0; fn < 4; ++fn) {
                const int lj = wn * 64 + fn * 16 + cid;
                const int j  = c0 + lj;
                const float s = acc[fm][fn][r];
                const float e = __expf((s - 1.0f) * INV_T);
                const bool dg = (j == i);            // only on diag tiles
                es += dg ? 0.f : e;
                cs += (!dg && (j != pj) && (s > pv)) ? 1.f : 0.f;
                col_e[fn] += e;
                const int pjc = (j + HALF) & (NROW - 1);
                col_c[fn] += ((i != pjc) && (s > pos_c[lj])) ? 1.f : 0.f;
            }
            // reduce over the 16 lanes sharing this row (low 4 lane bits)
            #pragma unroll
            for (int m = 1; m < 16; m <<= 1) {
                es += __shfl_xor(es, m);
                cs += __shfl_xor(cs, m);
            }
            if (cid == 0) {
                atom_addf(&sumexp[i], es);
                atom_addf(&cnt[i], cs);
            }
        }
    }

    // col pass: reduce over q (lane bits 4,5), atomic from q==0 lanes
    if (offdiag) {
        #pragma unroll
        for (int fn = 0; fn < 4; ++fn) {
            float ec = col_e[fn], cc = col_c[fn];
            ec += __shfl_xor(ec, 16); ec += __shfl_xor(ec, 32);
            cc += __shfl_xor(cc, 16); cc += __shfl_xor(cc, 32);
            if (q == 0) {
                const int j = c0 + wn * 64 + fn * 16 + cid;
                atom_addf(&sumexp[j], ec);
                atom_addf(&cnt[j], cc);
            }
        }
    }
}

// ---------------- finalize: ranks (fp32) + nll (last block writes mean) -------
// Sentinels: pos bad -> 60000 | sumexp==0 -> 40000 | cnt<0 -> 25000 | else rank.
__global__ void NCELoss_3126736191777_kernel(const float* __restrict__ cnt,
                                             const float* __restrict__ sumexp,
                                             const float* __restrict__ pos,
                                             float* __restrict__ out,
                                             float* __restrict__ nll_acc,
                                             int* __restrict__ done) {
    __shared__ float red[4];
    const int t = threadIdx.x;
    const int r = blockIdx.x * 256 + t;
    float c = cnt[r], se = sumexp[r], p = pos[r];
    float v;
    if (p != p || fabsf(p) > 1.05f) v = 60000.0f;
    else if (se == 0.0f)            v = 40000.0f;
    else if (c < 0.0f)              v = 25000.0f;
    else                            v = c;
    out[r] = v;
    float local = -p * INV_T + INV_T + __logf(se);
    #pragma unroll
    for (int m = 1; m < 64; m <<= 1) local += __shfl_xor(local, m);
    if ((t & 63) == 0) red[t >> 6] = local;
    __syncthreads();
    if (t == 0) {
        atom_addf(nll_acc, red[0] + red[1] + red[2] + red[3]);
        __threadfence();
        int ticket = __hip_atomic_fetch_add(done, 1, __ATOMIC_ACQ_REL,
                                            __HIP_MEMORY_SCOPE_AGENT);
        if (ticket == (int)gridDim.x - 1) {
            __threadfence();
            out[NROW] = nll_acc[0] / (float)NROW;
        }
    }
}

extern "C" void kernel_launch(void* const* d_in, const int* in_sizes, int n_in,
                              void* d_out, int out_size, void* d_ws, size_t ws_size,
                              hipStream_t stream) {
    (void)in_sizes; (void)n_in; (void)out_size; (void)ws_size;
    const float* x = (const float*)d_in[0];

    // ws: pos (32 KB) | sumexp (32 KB) | cnt (32 KB) | nll_acc+done (4 KB) | z bf16 (8 MB)
    char* base = (char*)d_ws;
    float* pos     = (float*)(base);
    float* sumexp  = (float*)(base + (size_t)NROW * 4);
    float* cnt     = (float*)(base + (size_t)NROW * 8);
    float* nll_acc = (float*)(base + (size_t)NROW * 12);
    int*   done    = (int*)(base + (size_t)NROW * 12 + 64);
    unsigned short* z = (unsigned short*)(base + (size_t)NROW * 12 + 4096);
    float* out = (float*)d_out;

    knormpos<<<NROW / 4, 256, 0, stream>>>(x, z, pos, sumexp, cnt, nll_acc, done);
    kgemm<<<2080, 512, 0, stream>>>(z, pos, sumexp, cnt);
    NCELoss_3126736191777_kernel<<<NROW / 256, 256, 0, stream>>>(cnt, sumexp, pos, out, nll_acc, done);
}